// Round 12
// baseline (809.006 us; speedup 1.0000x reference)
//
#include <hip/hip_runtime.h>
#include <hip/hip_cooperative_groups.h>
#include <hip/hip_bf16.h>
#include <cmath>

namespace cg = cooperative_groups;

#define F_IN 128
#define HDIM 64
#define NPB 128          // nodes per bucket (dst >> 7)
#define VNB 1024         // virtual partition chunks (blk_cnt stride)
#define CAP 2560         // fixed edge capacity per bucket (mean 2046, +11 sigma)

typedef __attribute__((ext_vector_type(8))) short bf16x8;
typedef __attribute__((ext_vector_type(4))) float f32x4;
typedef __attribute__((ext_vector_type(2))) float f32x2;

__device__ __forceinline__ float bf2f(unsigned short u) {
    union { unsigned int i; float f; } v; v.i = ((unsigned int)u) << 16; return v.f;
}
__device__ __forceinline__ unsigned short f2bf(float f) {
    __hip_bfloat16 h = __float2bfloat16(f);
    union { __hip_bfloat16 h; unsigned short u; } c; c.h = h; return c.u;
}
__device__ __forceinline__ unsigned char f2fp8(float f) {
    int p = __builtin_amdgcn_cvt_pk_fp8_f32(f, f, 0, false);
    return (unsigned char)(p & 0xff);
}
__device__ __forceinline__ void fp8x8_acc(uint2 v, float* a) {
    f32x2 f;
    f = __builtin_amdgcn_cvt_pk_f32_fp8(v.x, false); a[0] += f.x; a[1] += f.y;
    f = __builtin_amdgcn_cvt_pk_f32_fp8(v.x, true);  a[2] += f.x; a[3] += f.y;
    f = __builtin_amdgcn_cvt_pk_f32_fp8(v.y, false); a[4] += f.x; a[5] += f.y;
    f = __builtin_amdgcn_cvt_pk_f32_fp8(v.y, true);  a[6] += f.x; a[7] += f.y;
}

struct MegaParams {
    const float* x; const int* src; const int* dst; const int* batch;
    const float* W1; const float* b1; const float* W2; const float* b2;
    const float* Wl; const float* bl; float* out;
    int n, E, G, nbuk, chunk, ntiles, nslots;
    int* blk_cnt; int* bucket_cnt; int* pairs; int* colx;
    unsigned short* w1t; unsigned short* w2t;
    float* dinv; int4* slot_hdr;
    unsigned char* xws8; unsigned short* xh1; unsigned short* xh2;
    int* gstart;
};

// 34816 B shared scratch, overlaid per phase (sized by the K=128 matmul phase)
#define SMEM_BYTES 34816

__launch_bounds__(256, 4)
__global__ void mega_kernel(MegaParams p) {
    __shared__ __align__(16) char SMEM[SMEM_BYTES];
    cg::grid_group grid = cg::this_grid();
    int bid = blockIdx.x, tid = threadIdx.x;
    int nb = gridDim.x;

    // ================= phase 1: per-(chunk,bucket) histogram + W transpose =================
    {
        int* hist = (int*)SMEM;
        for (int vb = bid; vb < VNB; vb += nb) {
            for (int i = tid; i < p.nbuk; i += 256) hist[i] = 0;
            __syncthreads();
            int lo = vb * p.chunk, hi = min(p.E, lo + p.chunk);
            for (int e = lo + tid; e < hi; e += 256)
                atomicAdd(&hist[p.dst[e] >> 7], 1);
            __syncthreads();
            for (int i = tid; i < p.nbuk; i += 256)
                p.blk_cnt[(size_t)i * VNB + vb] = hist[i];
            __syncthreads();
        }
        int t = bid * 256 + tid;
        if (t < F_IN * 64) {
            int c = t & 63, k = t >> 6;
            p.w1t[c * F_IN + k] = f2bf(p.W1[t]);
        } else if (t < F_IN * 64 + HDIM * 64) {
            int u = t - F_IN * 64;
            int c = u & 63, k = u >> 6;
            p.w2t[c * HDIM + k] = f2bf(p.W2[u]);
        }
    }
    grid.sync();

    // ================= phase 2: per-bucket scan over chunks + graph bounds =================
    {
        int* sd = (int*)SMEM;
        for (int b = bid; b < p.nbuk; b += nb) {
            int4* row = (int4*)(p.blk_cnt + (size_t)b * VNB);   // 256 int4
            int4 v = row[tid];
            int s0 = v.x, s1 = s0 + v.y, s2 = s1 + v.z, s3 = s2 + v.w;
            sd[tid] = s3;
            __syncthreads();
            for (int off = 1; off < 256; off <<= 1) {
                int a = (tid >= off) ? sd[tid - off] : 0;
                __syncthreads();
                sd[tid] += a;
                __syncthreads();
            }
            int base = sd[tid] - s3;
            int4 o; o.x = base; o.y = base + s0; o.z = base + s1; o.w = base + s2;
            row[tid] = o;
            if (tid == 255) p.bucket_cnt[b] = sd[255];
            __syncthreads();
        }
        int g = bid * 256 + tid;
        if (g <= p.G) {
            int lo = 0, hi = p.n;
            while (lo < hi) {
                int mid = (lo + hi) >> 1;
                if (p.batch[mid] < g) lo = mid + 1; else hi = mid;
            }
            p.gstart[g] = lo;
        }
    }
    grid.sync();

    // ================= phase 3: place edges into bucket-grouped packed ints =================
    {
        int* cur = (int*)SMEM;
        for (int vb = bid; vb < VNB; vb += nb) {
            for (int i = tid; i < p.nbuk; i += 256)
                cur[i] = i * CAP + p.blk_cnt[(size_t)i * VNB + vb];
            __syncthreads();
            int lo = vb * p.chunk, hi = min(p.E, lo + p.chunk);
            for (int e = lo + tid; e < hi; e += 256) {
                int d = p.dst[e];
                int pos = atomicAdd(&cur[d >> 7], 1);
                p.pairs[pos] = (p.src[e] << 7) | (d & 127);
            }
            __syncthreads();
        }
    }
    grid.sync();

    // ================= phase 4: per-bucket local CSR + degree-sorted slot headers ==========
    {
        int* dl  = (int*)SMEM;
        int* sc  = dl + 128;
        int* cu  = sc + 128;
        int* h64 = cu + 128;
        int* s64 = h64 + 64;
        for (int b = bid; b < p.nbuk; b += nb) {
            int nlo = b << 7;
            int eb = b * CAP;
            int ee = eb + p.bucket_cnt[b];
            if (tid < 128) dl[tid] = 0;
            if (tid < 64) h64[tid] = 0;
            __syncthreads();
            for (int e = eb + tid; e < ee; e += 256)
                atomicAdd(&dl[p.pairs[e] & 127], 1);
            __syncthreads();
            int d0 = 0, excl = 0;
            if (tid < 128) { d0 = dl[tid]; sc[tid] = d0; }
            __syncthreads();
            for (int off = 1; off < 128; off <<= 1) {
                int a = (tid >= off && tid < 128) ? sc[tid - off] : 0;
                __syncthreads();
                if (tid < 128) sc[tid] += a;
                __syncthreads();
            }
            if (tid < 128) {
                excl = sc[tid] - d0;
                int node = nlo + tid;
                float dv = rsqrtf((float)(d0 + 1));
                if (node < p.n) p.dinv[node] = dv;
                cu[tid] = eb + excl;
                atomicAdd(&h64[min(d0, 63)], 1);
            }
            __syncthreads();
            if (tid == 0) { int run = 0; for (int i = 0; i < 64; ++i) { s64[i] = run; run += h64[i]; } }
            __syncthreads();
            if (tid < 64) h64[tid] = 0;
            __syncthreads();
            if (tid < 128) {
                int node = nlo + tid;
                int bin = min(d0, 63);
                int pos = s64[bin] + atomicAdd(&h64[bin], 1);
                int4 hdr;
                hdr.x = (node < p.n) ? node : 0x7fffffff;
                hdr.y = eb + excl;
                hdr.z = d0;
                hdr.w = __float_as_int(rsqrtf((float)(d0 + 1)));
                p.slot_hdr[nlo + pos] = hdr;
            }
            __syncthreads();
            for (int e = eb + tid; e < ee; e += 256) {
                unsigned int v = (unsigned int)p.pairs[e];
                int pos = atomicAdd(&cu[v & 127], 1);
                p.colx[pos] = (int)(v >> 7);
            }
            __syncthreads();
        }
    }
    grid.sync();

    // ================= phase 5: matmul1 (f32 x, K=128) -> fp8 xws8 =================
    {
        constexpr int K = F_IN, KS = K / 32, LDX = K + 8;
        unsigned short* Xs = (unsigned short*)SMEM;
        unsigned short* Ws = (unsigned short*)(SMEM + 64 * LDX * 2);
        int wave = tid >> 6, lane = tid & 63;
        int q = lane >> 4, nn = lane & 15;
        for (int tile = bid; tile < p.ntiles; tile += nb) {
            int rowbase = tile * 64;
            for (int i = tid; i < 64 * (K / 8); i += 256) {
                int r = i / (K / 8), ch = i % (K / 8);
                *(bf16x8*)(Ws + r * LDX + ch * 8) = ((const bf16x8*)p.w1t)[i];
            }
            const float4* X4 = (const float4*)p.x;
            for (int i = tid; i < 64 * (K / 4); i += 256) {
                int r = i / (K / 4), k4 = i % (K / 4);
                ushort4 u = { 0, 0, 0, 0 };
                int gr = rowbase + r;
                if (gr < p.n) {
                    float4 v = X4[(size_t)gr * (K / 4) + k4];
                    u.x = f2bf(v.x); u.y = f2bf(v.y); u.z = f2bf(v.z); u.w = f2bf(v.w);
                }
                *(ushort4*)(Xs + r * LDX + k4 * 4) = u;
            }
            __syncthreads();
            f32x4 acc[4] = {{0,0,0,0},{0,0,0,0},{0,0,0,0},{0,0,0,0}};
            int mrow = wave * 16 + nn;
#pragma unroll
            for (int s = 0; s < KS; ++s) {
                bf16x8 af = *(const bf16x8*)(Xs + mrow * LDX + s * 32 + q * 8);
#pragma unroll
                for (int c = 0; c < 4; ++c) {
                    bf16x8 bf = *(const bf16x8*)(Ws + (c * 16 + nn) * LDX + s * 32 + q * 8);
                    acc[c] = __builtin_amdgcn_mfma_f32_16x16x32_bf16(af, bf, acc[c], 0, 0, 0);
                }
            }
#pragma unroll
            for (int r = 0; r < 4; ++r) {
                int row = rowbase + wave * 16 + q * 4 + r;
                if (row >= p.n) continue;
                float dv = p.dinv[row];
#pragma unroll
                for (int c = 0; c < 4; ++c)
                    p.xws8[(size_t)row * HDIM + c * 16 + nn] = f2fp8(acc[c][r] * dv);
            }
            __syncthreads();
        }
    }
    grid.sync();

    // ================= phase 6: gather1 (fp8 rows) -> bf16 xh1 =================
    {
        const uint2* xws = (const uint2*)p.xws8;
        for (int t = bid * 256 + tid; t < p.nslots * 8; t += nb * 256) {
            int slot = t >> 3, L = t & 7;
            int4 hdr = p.slot_hdr[slot];
            int node = hdr.x;
            if (node >= p.n) continue;
            int s = hdr.y, end = s + hdr.z;
            float dv = __int_as_float(hdr.w);
            float a[8] = {0, 0, 0, 0, 0, 0, 0, 0};
            fp8x8_acc(xws[(size_t)node * 8 + L], a);
            int e = s;
            for (; e + 8 <= end; e += 8) {
                uint2 v0 = xws[(size_t)p.colx[e + 0] * 8 + L];
                uint2 v1 = xws[(size_t)p.colx[e + 1] * 8 + L];
                uint2 v2 = xws[(size_t)p.colx[e + 2] * 8 + L];
                uint2 v3 = xws[(size_t)p.colx[e + 3] * 8 + L];
                uint2 v4 = xws[(size_t)p.colx[e + 4] * 8 + L];
                uint2 v5 = xws[(size_t)p.colx[e + 5] * 8 + L];
                uint2 v6 = xws[(size_t)p.colx[e + 6] * 8 + L];
                uint2 v7 = xws[(size_t)p.colx[e + 7] * 8 + L];
                fp8x8_acc(v0, a); fp8x8_acc(v1, a); fp8x8_acc(v2, a); fp8x8_acc(v3, a);
                fp8x8_acc(v4, a); fp8x8_acc(v5, a); fp8x8_acc(v6, a); fp8x8_acc(v7, a);
            }
            for (; e < end; ++e)
                fp8x8_acc(xws[(size_t)p.colx[e] * 8 + L], a);
            int f0 = L * 8;
            bf16x8 o;
#pragma unroll
            for (int j = 0; j < 8; ++j)
                o[j] = (short)f2bf(fmaxf(fmaf(a[j], dv, p.b1[f0 + j]), 0.0f));
            ((bf16x8*)p.xh1)[(size_t)node * 8 + L] = o;
        }
    }
    grid.sync();

    // ================= phase 7: matmul2 (bf16 xh1, K=64) -> fp8 xws8 =================
    {
        constexpr int K = HDIM, KS = K / 32, LDX = K + 8;
        unsigned short* Xs = (unsigned short*)SMEM;
        unsigned short* Ws = (unsigned short*)(SMEM + 64 * LDX * 2);
        int wave = tid >> 6, lane = tid & 63;
        int q = lane >> 4, nn = lane & 15;
        for (int tile = bid; tile < p.ntiles; tile += nb) {
            int rowbase = tile * 64;
            for (int i = tid; i < 64 * (K / 8); i += 256) {
                int r = i / (K / 8), ch = i % (K / 8);
                *(bf16x8*)(Ws + r * LDX + ch * 8) = ((const bf16x8*)p.w2t)[i];
            }
            for (int i = tid; i < 64 * 8; i += 256) {
                int r = i >> 3, c = i & 7;
                int gr = rowbase + r;
                bf16x8 u;
                if (gr < p.n) u = ((const bf16x8*)p.xh1)[(size_t)gr * 8 + c];
                else { short z[8] = {0,0,0,0,0,0,0,0}; u = *(bf16x8*)z; }
                *(bf16x8*)(Xs + r * LDX + c * 8) = u;
            }
            __syncthreads();
            f32x4 acc[4] = {{0,0,0,0},{0,0,0,0},{0,0,0,0},{0,0,0,0}};
            int mrow = wave * 16 + nn;
#pragma unroll
            for (int s = 0; s < KS; ++s) {
                bf16x8 af = *(const bf16x8*)(Xs + mrow * LDX + s * 32 + q * 8);
#pragma unroll
                for (int c = 0; c < 4; ++c) {
                    bf16x8 bf = *(const bf16x8*)(Ws + (c * 16 + nn) * LDX + s * 32 + q * 8);
                    acc[c] = __builtin_amdgcn_mfma_f32_16x16x32_bf16(af, bf, acc[c], 0, 0, 0);
                }
            }
#pragma unroll
            for (int r = 0; r < 4; ++r) {
                int row = rowbase + wave * 16 + q * 4 + r;
                if (row >= p.n) continue;
                float dv = p.dinv[row];
#pragma unroll
                for (int c = 0; c < 4; ++c)
                    p.xws8[(size_t)row * HDIM + c * 16 + nn] = f2fp8(acc[c][r] * dv);
            }
            __syncthreads();
        }
    }
    grid.sync();

    // ================= phase 8: gather2 (fp8 rows) -> bf16 xh2 =================
    {
        const uint2* xws = (const uint2*)p.xws8;
        for (int t = bid * 256 + tid; t < p.nslots * 8; t += nb * 256) {
            int slot = t >> 3, L = t & 7;
            int4 hdr = p.slot_hdr[slot];
            int node = hdr.x;
            if (node >= p.n) continue;
            int s = hdr.y, end = s + hdr.z;
            float dv = __int_as_float(hdr.w);
            float a[8] = {0, 0, 0, 0, 0, 0, 0, 0};
            fp8x8_acc(xws[(size_t)node * 8 + L], a);
            int e = s;
            for (; e + 8 <= end; e += 8) {
                uint2 v0 = xws[(size_t)p.colx[e + 0] * 8 + L];
                uint2 v1 = xws[(size_t)p.colx[e + 1] * 8 + L];
                uint2 v2 = xws[(size_t)p.colx[e + 2] * 8 + L];
                uint2 v3 = xws[(size_t)p.colx[e + 3] * 8 + L];
                uint2 v4 = xws[(size_t)p.colx[e + 4] * 8 + L];
                uint2 v5 = xws[(size_t)p.colx[e + 5] * 8 + L];
                uint2 v6 = xws[(size_t)p.colx[e + 6] * 8 + L];
                uint2 v7 = xws[(size_t)p.colx[e + 7] * 8 + L];
                fp8x8_acc(v0, a); fp8x8_acc(v1, a); fp8x8_acc(v2, a); fp8x8_acc(v3, a);
                fp8x8_acc(v4, a); fp8x8_acc(v5, a); fp8x8_acc(v6, a); fp8x8_acc(v7, a);
            }
            for (; e < end; ++e)
                fp8x8_acc(xws[(size_t)p.colx[e] * 8 + L], a);
            int f0 = L * 8;
            bf16x8 o;
#pragma unroll
            for (int j = 0; j < 8; ++j)
                o[j] = (short)f2bf(fmaxf(fmaf(a[j], dv, p.b2[f0 + j]), 0.0f));
            ((bf16x8*)p.xh2)[(size_t)node * 8 + L] = o;
        }
    }
    grid.sync();

    // ================= phase 9: mean-pool + head + sigmoid =================
    {
        float (*red)[HDIM] = (float(*)[HDIM])SMEM;
        int f = tid & 63, rg = tid >> 6;
        for (int g = bid; g < p.G; g += nb) {
            int s = p.gstart[g], e = p.gstart[g + 1];
            float acc = 0.0f;
            for (int i = s + rg; i < e; i += 4)
                acc += bf2f(p.xh2[(size_t)i * HDIM + f]);
            red[rg][f] = acc;
            __syncthreads();
            if (rg == 0) {
                float v = (red[0][f] + red[1][f]) + (red[2][f] + red[3][f]);
                float c = fmaxf((float)(e - s), 1.0f);
                v = v * p.Wl[f] * (1.0f / c);
#pragma unroll
                for (int off = 32; off; off >>= 1) v += __shfl_down(v, off, 64);
                if (f == 0) p.out[g] = 1.0f / (1.0f + expf(-(v + p.bl[0])));
            }
            __syncthreads();
        }
    }
}

// ---------------- launch ----------------

extern "C" void kernel_launch(void* const* d_in, const int* in_sizes, int n_in,
                              void* d_out, int out_size, void* d_ws, size_t ws_size,
                              hipStream_t stream) {
    const int n = in_sizes[0] / F_IN;   // 100000
    const int E = in_sizes[1] / 2;      // 1600000
    const int G = out_size;             // 512
    int nbuk = (n + NPB - 1) / NPB;     // 782

    // workspace layout
    char* wsb = (char*)d_ws;
    auto alloc = [&](size_t bytes) { char* p = wsb; wsb += (bytes + 255) & ~(size_t)255; return p; };
    MegaParams p;
    p.x = (const float*)d_in[0];
    p.src = (const int*)d_in[1];
    p.dst = p.src + E;
    p.batch = (const int*)d_in[2];
    p.W1 = (const float*)d_in[3];
    p.b1 = (const float*)d_in[4];
    p.W2 = (const float*)d_in[5];
    p.b2 = (const float*)d_in[6];
    p.Wl = (const float*)d_in[7];
    p.bl = (const float*)d_in[8];
    p.out = (float*)d_out;
    p.n = n; p.E = E; p.G = G; p.nbuk = nbuk;
    p.chunk = (E + VNB - 1) / VNB;      // 1563
    p.ntiles = (n + 63) / 64;           // 1563
    p.nslots = nbuk * NPB;              // 100096

    p.dinv       = (float*)alloc((size_t)n * 4);
    p.slot_hdr   = (int4*)alloc((size_t)p.nslots * 16);
    p.bucket_cnt = (int*)alloc(1024 * 4);
    p.blk_cnt    = (int*)alloc((size_t)nbuk * VNB * 4);
    p.pairs      = (int*)alloc((size_t)nbuk * CAP * 4);
    p.colx       = (int*)alloc((size_t)nbuk * CAP * 4);
    p.w1t        = (unsigned short*)alloc((size_t)F_IN * HDIM * 2);
    p.w2t        = (unsigned short*)alloc((size_t)HDIM * HDIM * 2);
    p.xws8       = (unsigned char*)alloc((size_t)n * HDIM);
    p.xh1        = (unsigned short*)alloc((size_t)n * HDIM * 2);
    p.xh2        = (unsigned short*)alloc((size_t)n * HDIM * 2);
    p.gstart     = (int*)alloc(((size_t)G + 1) * 4);

    // co-residency-safe grid: blocks/CU from occupancy query x CU count, cap 1024
    int maxb = 0;
    hipOccupancyMaxActiveBlocksPerMultiprocessor(&maxb, (const void*)mega_kernel, 256, 0);
    if (maxb < 1) maxb = 1;
    hipDeviceProp_t prop;
    hipGetDeviceProperties(&prop, 0);
    int grid = maxb * prop.multiProcessorCount;
    if (grid > 1024) grid = 1024;

    void* args[] = { (void*)&p };
    hipLaunchCooperativeKernel((const void*)mega_kernel, dim3(grid), dim3(256),
                               args, 0, stream);
}

// Round 13
// 246.470 us; speedup vs baseline: 3.2824x; 3.2824x over previous
//
#include <hip/hip_runtime.h>
#include <hip/hip_bf16.h>
#include <cmath>

#define F_IN 128
#define HDIM 64
#define NPB 128          // nodes per bucket (dst >> 7)
#define NB1 512          // partition chunks (p0 / p1_place)
#define CAP 2560         // fixed edge capacity per bucket (mean 2046, +11 sigma)

typedef __attribute__((ext_vector_type(8))) short bf16x8;
typedef __attribute__((ext_vector_type(4))) float f32x4;
typedef __attribute__((ext_vector_type(2))) float f32x2;

__device__ __forceinline__ float bf2f(unsigned short u) {
    union { unsigned int i; float f; } v; v.i = ((unsigned int)u) << 16; return v.f;
}
__device__ __forceinline__ unsigned short f2bf(float f) {
    __hip_bfloat16 h = __float2bfloat16(f);
    union { __hip_bfloat16 h; unsigned short u; } c; c.h = h; return c.u;
}
__device__ __forceinline__ unsigned char f2fp8(float f) {
    int p = __builtin_amdgcn_cvt_pk_fp8_f32(f, f, 0, false);
    return (unsigned char)(p & 0xff);
}
// a[j] += s * decode(v)[j]
__device__ __forceinline__ void fp8x8_fma(uint2 v, float s, float* a) {
    f32x2 f;
    f = __builtin_amdgcn_cvt_pk_f32_fp8(v.x, false); a[0] += s * f.x; a[1] += s * f.y;
    f = __builtin_amdgcn_cvt_pk_f32_fp8(v.x, true);  a[2] += s * f.x; a[3] += s * f.y;
    f = __builtin_amdgcn_cvt_pk_f32_fp8(v.y, false); a[4] += s * f.x; a[5] += s * f.y;
    f = __builtin_amdgcn_cvt_pk_f32_fp8(v.y, true);  a[6] += s * f.x; a[7] += s * f.y;
}
__device__ __forceinline__ void fp8x8_acc(uint2 v, float* a) {
    f32x2 f;
    f = __builtin_amdgcn_cvt_pk_f32_fp8(v.x, false); a[0] += f.x; a[1] += f.y;
    f = __builtin_amdgcn_cvt_pk_f32_fp8(v.x, true);  a[2] += f.x; a[3] += f.y;
    f = __builtin_amdgcn_cvt_pk_f32_fp8(v.y, false); a[4] += f.x; a[5] += f.y;
    f = __builtin_amdgcn_cvt_pk_f32_fp8(v.y, true);  a[6] += f.x; a[7] += f.y;
}

// ================= K1: fused front (independent roles, no intra-kernel deps) =================
// blocks [0,NB1):               per-(chunk,bucket) dst histogram
// blocks [NB1, NB1+MMB):        matmul1: xws8 = fp8(X @ W1)   (UNscaled; dinv applied in gather1)
// blocks [NB1+MMB, +16):        w2t[c][k] = bf16(W2[k][c])
// blocks [NB1+MMB+16, +3):      gstart[g] = lower_bound(batch, g)

__launch_bounds__(256)
__global__ void fused_front(const int* __restrict__ dst, int* __restrict__ blk_cnt,
                            int E, int nbuk, int chunk,
                            const float* __restrict__ X, const float* __restrict__ W1,
                            unsigned char* __restrict__ xws8, int ntiles, int n,
                            const float* __restrict__ W2, unsigned short* __restrict__ w2t,
                            const int* __restrict__ batch, int* __restrict__ gstart, int G) {
    __shared__ __align__(16) char SMEM[34816];
    int tid = threadIdx.x, bid = blockIdx.x;

    if (bid < NB1) {                                    // ---- role: histogram ----
        int* hist = (int*)SMEM;
        for (int i = tid; i < nbuk; i += 256) hist[i] = 0;
        __syncthreads();
        int lo = bid * chunk, hi = min(E, lo + chunk);
        for (int e = lo + tid; e < hi; e += 256)
            atomicAdd(&hist[dst[e] >> 7], 1);
        __syncthreads();
        for (int i = tid; i < nbuk; i += 256)
            blk_cnt[(size_t)i * NB1 + bid] = hist[i];
        return;
    }
    if (bid < NB1 + ntiles) {                           // ---- role: matmul1 (K=128) ----
        constexpr int K = F_IN, KS = K / 32, LDX = K + 8;
        unsigned short* Xs = (unsigned short*)SMEM;
        unsigned short* Ws = (unsigned short*)(SMEM + 64 * LDX * 2);
        int rowbase = (bid - NB1) * 64;
        for (int i = tid; i < K * 64; i += 256) {       // stage W1 transposed f32->bf16
            int k = i >> 6, c = i & 63;
            Ws[c * LDX + k] = f2bf(W1[i]);
        }
        const float4* X4 = (const float4*)X;
        for (int i = tid; i < 64 * (K / 4); i += 256) {
            int r = i / (K / 4), k4 = i % (K / 4);
            ushort4 u = { 0, 0, 0, 0 };
            int gr = rowbase + r;
            if (gr < n) {
                float4 v = X4[(size_t)gr * (K / 4) + k4];
                u.x = f2bf(v.x); u.y = f2bf(v.y); u.z = f2bf(v.z); u.w = f2bf(v.w);
            }
            *(ushort4*)(Xs + r * LDX + k4 * 4) = u;
        }
        __syncthreads();
        int wave = tid >> 6, lane = tid & 63;
        int q = lane >> 4, nn = lane & 15;
        f32x4 acc[4] = {{0,0,0,0},{0,0,0,0},{0,0,0,0},{0,0,0,0}};
        int mrow = wave * 16 + nn;
#pragma unroll
        for (int s = 0; s < KS; ++s) {
            bf16x8 af = *(const bf16x8*)(Xs + mrow * LDX + s * 32 + q * 8);
#pragma unroll
            for (int c = 0; c < 4; ++c) {
                bf16x8 bf = *(const bf16x8*)(Ws + (c * 16 + nn) * LDX + s * 32 + q * 8);
                acc[c] = __builtin_amdgcn_mfma_f32_16x16x32_bf16(af, bf, acc[c], 0, 0, 0);
            }
        }
#pragma unroll
        for (int r = 0; r < 4; ++r) {
            int row = rowbase + wave * 16 + q * 4 + r;
            if (row >= n) continue;
#pragma unroll
            for (int c = 0; c < 4; ++c)
                xws8[(size_t)row * HDIM + c * 16 + nn] = f2fp8(acc[c][r]);
        }
        return;
    }
    if (bid < NB1 + ntiles + 16) {                      // ---- role: W2 transpose ----
        int t = (bid - NB1 - ntiles) * 256 + tid;       // t < 4096
        int c = t & 63, k = t >> 6;
        w2t[c * HDIM + k] = f2bf(W2[t]);
        return;
    }
    {                                                   // ---- role: graph bounds ----
        int g = (bid - NB1 - ntiles - 16) * 256 + tid;
        if (g > G) return;
        int lo = 0, hi = n;
        while (lo < hi) {
            int mid = (lo + hi) >> 1;
            if (batch[mid] < g) lo = mid + 1; else hi = mid;
        }
        gstart[g] = lo;
    }
}

// ================= K2: per-bucket scan over chunks =================

__launch_bounds__(256)
__global__ void p_scan_blocks(int* __restrict__ blk_cnt, int* __restrict__ bucket_cnt) {
    __shared__ int sd[256];
    int b = blockIdx.x, tid = threadIdx.x;
    int2* row = (int2*)(blk_cnt + (size_t)b * NB1);
    int2 v = row[tid];
    int s0 = v.x, s1 = s0 + v.y;
    sd[tid] = s1;
    __syncthreads();
    for (int off = 1; off < 256; off <<= 1) {
        int a = (tid >= off) ? sd[tid - off] : 0;
        __syncthreads();
        sd[tid] += a;
        __syncthreads();
    }
    int base = sd[tid] - s1;
    row[tid] = make_int2(base, base + s0);
    if (tid == 255) bucket_cnt[b] = sd[255];
}

// ================= K3: place edges (fixed bucket base, LDS-only atomics) =================

__launch_bounds__(256)
__global__ void p1_place(const int* __restrict__ src, const int* __restrict__ dst,
                         const int* __restrict__ blk_cnt, int* __restrict__ pairs,
                         int E, int nbuk, int chunk) {
    __shared__ int cur[1024];
    int tid = threadIdx.x;
    for (int i = tid; i < nbuk; i += 256)
        cur[i] = i * CAP + blk_cnt[(size_t)i * NB1 + blockIdx.x];
    __syncthreads();
    int lo = blockIdx.x * chunk, hi = min(E, lo + chunk);
    for (int e = lo + tid; e < hi; e += 256) {
        int d = dst[e];
        int pos = atomicAdd(&cur[d >> 7], 1);
        pairs[pos] = (src[e] << 7) | (d & 127);
    }
}

// ================= K4: per-bucket local CSR + degree-sorted slot headers =================

__launch_bounds__(256)
__global__ void p2_csr(const int* __restrict__ pairs, const int* __restrict__ bucket_cnt,
                       float* __restrict__ dinv, int* __restrict__ col,
                       int4* __restrict__ slot_hdr, int n) {
    __shared__ int dl[128];
    __shared__ int sc[128];
    __shared__ int cur[128];
    __shared__ int h64[64];
    __shared__ int s64[64];
    int b = blockIdx.x, tid = threadIdx.x;
    int nlo = b << 7;
    int eb = b * CAP;
    int ee = eb + bucket_cnt[b];
    if (tid < 128) dl[tid] = 0;
    if (tid < 64) h64[tid] = 0;
    __syncthreads();
    for (int e = eb + tid; e < ee; e += 256)
        atomicAdd(&dl[pairs[e] & 127], 1);
    __syncthreads();
    int d0 = 0, excl = 0;
    if (tid < 128) { d0 = dl[tid]; sc[tid] = d0; }
    __syncthreads();
    for (int off = 1; off < 128; off <<= 1) {
        int a = (tid >= off && tid < 128) ? sc[tid - off] : 0;
        __syncthreads();
        if (tid < 128) sc[tid] += a;
        __syncthreads();
    }
    if (tid < 128) {
        excl = sc[tid] - d0;
        int node = nlo + tid;
        float dv = rsqrtf((float)(d0 + 1));
        if (node < n) dinv[node] = dv;
        cur[tid] = eb + excl;
        atomicAdd(&h64[min(d0, 63)], 1);
    }
    __syncthreads();
    if (tid == 0) { int run = 0; for (int i = 0; i < 64; ++i) { s64[i] = run; run += h64[i]; } }
    __syncthreads();
    if (tid < 64) h64[tid] = 0;
    __syncthreads();
    if (tid < 128) {
        int node = nlo + tid;
        int bin = min(d0, 63);
        int pos = s64[bin] + atomicAdd(&h64[bin], 1);
        int4 hdr;
        hdr.x = (node < n) ? node : 0x7fffffff;
        hdr.y = eb + excl;
        hdr.z = d0;
        hdr.w = __float_as_int(rsqrtf((float)(d0 + 1)));
        slot_hdr[nlo + pos] = hdr;
    }
    __syncthreads();
    for (int e = eb + tid; e < ee; e += 256) {
        unsigned int v = (unsigned int)pairs[e];
        int pos = atomicAdd(&cur[v & 127], 1);
        col[pos] = (int)(v >> 7);
    }
}

// ================= K5: gather1 — fp8 UNscaled rows, per-edge dinv[src] =================
// xh1 = bf16(relu(dinv_i*(dinv_i*xw[i] + sum_e dinv[c_e]*xw[c_e]) + b1))

__launch_bounds__(256)
__global__ void csr_gather8_fp8d(const int4* __restrict__ slot_hdr, const int* __restrict__ col,
                                 const float* __restrict__ dinv, const uint2* __restrict__ xws,
                                 const float* __restrict__ bias, bf16x8* __restrict__ outb,
                                 int nslots, int n) {
    int t = blockIdx.x * 256 + threadIdx.x;
    int slot = t >> 3;
    if (slot >= nslots) return;
    int L = t & 7;
    int4 hdr = slot_hdr[slot];
    int node = hdr.x;
    if (node >= n) return;
    int s = hdr.y, end = s + hdr.z;
    float dv = __int_as_float(hdr.w);

    float a[8] = {0, 0, 0, 0, 0, 0, 0, 0};
    fp8x8_fma(xws[(size_t)node * 8 + L], dv, a);   // self term: dv * xw[node]

    int e = s;
    for (; e + 8 <= end; e += 8) {
        int c0 = col[e + 0], c1 = col[e + 1], c2 = col[e + 2], c3 = col[e + 3];
        int c4 = col[e + 4], c5 = col[e + 5], c6 = col[e + 6], c7 = col[e + 7];
        float d0 = dinv[c0], d1 = dinv[c1], d2 = dinv[c2], d3 = dinv[c3];
        float d4 = dinv[c4], d5 = dinv[c5], d6 = dinv[c6], d7 = dinv[c7];
        uint2 v0 = xws[(size_t)c0 * 8 + L];
        uint2 v1 = xws[(size_t)c1 * 8 + L];
        uint2 v2 = xws[(size_t)c2 * 8 + L];
        uint2 v3 = xws[(size_t)c3 * 8 + L];
        uint2 v4 = xws[(size_t)c4 * 8 + L];
        uint2 v5 = xws[(size_t)c5 * 8 + L];
        uint2 v6 = xws[(size_t)c6 * 8 + L];
        uint2 v7 = xws[(size_t)c7 * 8 + L];
        fp8x8_fma(v0, d0, a); fp8x8_fma(v1, d1, a); fp8x8_fma(v2, d2, a); fp8x8_fma(v3, d3, a);
        fp8x8_fma(v4, d4, a); fp8x8_fma(v5, d5, a); fp8x8_fma(v6, d6, a); fp8x8_fma(v7, d7, a);
    }
    for (; e < end; ++e) {
        int c = col[e];
        fp8x8_fma(xws[(size_t)c * 8 + L], dinv[c], a);
    }

    int f0 = L * 8;
    bf16x8 o;
#pragma unroll
    for (int j = 0; j < 8; ++j)
        o[j] = (short)f2bf(fmaxf(fmaf(a[j], dv, bias[f0 + j]), 0.0f));
    outb[(size_t)node * 8 + L] = o;
}

// ================= K6: matmul2 (bf16 xh1, K=64) -> fp8 scaled by dinv =================

__launch_bounds__(256)
__global__ void matmul_mfma_b16(const unsigned short* __restrict__ X,
                                const unsigned short* __restrict__ Wt,
                                const float* __restrict__ dinv, unsigned char* __restrict__ out,
                                int n) {
    constexpr int K = 64, KS = 2, LDX = K + 8;
    __shared__ unsigned short Xs[64 * LDX];
    __shared__ unsigned short Ws[64 * LDX];
    int tid = threadIdx.x;
    int rowbase = blockIdx.x * 64;
    for (int i = tid; i < 64 * (K / 8); i += 256) {
        int r = i / (K / 8), ch = i % (K / 8);
        *(bf16x8*)(Ws + r * LDX + ch * 8) = ((const bf16x8*)Wt)[i];
    }
    for (int i = tid; i < 64 * 8; i += 256) {
        int r = i >> 3, c = i & 7;
        int gr = rowbase + r;
        bf16x8 u;
        if (gr < n) u = ((const bf16x8*)X)[(size_t)gr * 8 + c];
        else { short z[8] = {0,0,0,0,0,0,0,0}; u = *(bf16x8*)z; }
        *(bf16x8*)(Xs + r * LDX + c * 8) = u;
    }
    __syncthreads();
    int wave = tid >> 6, lane = tid & 63;
    int q = lane >> 4, nn = lane & 15;
    f32x4 acc[4] = {{0,0,0,0},{0,0,0,0},{0,0,0,0},{0,0,0,0}};
    int mrow = wave * 16 + nn;
#pragma unroll
    for (int s = 0; s < KS; ++s) {
        bf16x8 af = *(const bf16x8*)(Xs + mrow * LDX + s * 32 + q * 8);
#pragma unroll
        for (int c = 0; c < 4; ++c) {
            bf16x8 bf = *(const bf16x8*)(Ws + (c * 16 + nn) * LDX + s * 32 + q * 8);
            acc[c] = __builtin_amdgcn_mfma_f32_16x16x32_bf16(af, bf, acc[c], 0, 0, 0);
        }
    }
#pragma unroll
    for (int r = 0; r < 4; ++r) {
        int row = rowbase + wave * 16 + q * 4 + r;
        if (row >= n) continue;
        float dv = dinv[row];
#pragma unroll
        for (int c = 0; c < 4; ++c)
            out[(size_t)row * HDIM + c * 16 + nn] = f2fp8(acc[c][r] * dv);
    }
}

// ================= K7: gather2 — fp8 pre-scaled rows (as R11) =================

__launch_bounds__(256)
__global__ void csr_gather8_fp8(const int4* __restrict__ slot_hdr, const int* __restrict__ col,
                                const uint2* __restrict__ xws, const float* __restrict__ bias,
                                bf16x8* __restrict__ outb, int nslots, int n) {
    int t = blockIdx.x * 256 + threadIdx.x;
    int slot = t >> 3;
    if (slot >= nslots) return;
    int L = t & 7;
    int4 hdr = slot_hdr[slot];
    int node = hdr.x;
    if (node >= n) return;
    int s = hdr.y, end = s + hdr.z;
    float dv = __int_as_float(hdr.w);

    float a[8] = {0, 0, 0, 0, 0, 0, 0, 0};
    fp8x8_acc(xws[(size_t)node * 8 + L], a);

    int e = s;
    for (; e + 8 <= end; e += 8) {
        uint2 v0 = xws[(size_t)col[e + 0] * 8 + L];
        uint2 v1 = xws[(size_t)col[e + 1] * 8 + L];
        uint2 v2 = xws[(size_t)col[e + 2] * 8 + L];
        uint2 v3 = xws[(size_t)col[e + 3] * 8 + L];
        uint2 v4 = xws[(size_t)col[e + 4] * 8 + L];
        uint2 v5 = xws[(size_t)col[e + 5] * 8 + L];
        uint2 v6 = xws[(size_t)col[e + 6] * 8 + L];
        uint2 v7 = xws[(size_t)col[e + 7] * 8 + L];
        fp8x8_acc(v0, a); fp8x8_acc(v1, a); fp8x8_acc(v2, a); fp8x8_acc(v3, a);
        fp8x8_acc(v4, a); fp8x8_acc(v5, a); fp8x8_acc(v6, a); fp8x8_acc(v7, a);
    }
    for (; e < end; ++e)
        fp8x8_acc(xws[(size_t)col[e] * 8 + L], a);

    int f0 = L * 8;
    bf16x8 o;
#pragma unroll
    for (int j = 0; j < 8; ++j)
        o[j] = (short)f2bf(fmaxf(fmaf(a[j], dv, bias[f0 + j]), 0.0f));
    outb[(size_t)node * 8 + L] = o;
}

// ================= K8: mean-pool (bf16 rows) + head + sigmoid =================

__launch_bounds__(256)
__global__ void pool_head(const unsigned short* __restrict__ h, const int* __restrict__ gstart,
                          const float* __restrict__ Wl, const float* __restrict__ bl,
                          float* __restrict__ out, int G) {
    int g = blockIdx.x;
    int s = gstart[g], e = gstart[g + 1];
    int f  = threadIdx.x & 63;
    int rg = threadIdx.x >> 6;
    float acc = 0.0f;
    for (int i = s + rg; i < e; i += 4)
        acc += bf2f(h[(size_t)i * HDIM + f]);
    __shared__ float red[4][HDIM];
    red[rg][f] = acc;
    __syncthreads();
    if (rg == 0) {
        float v = (red[0][f] + red[1][f]) + (red[2][f] + red[3][f]);
        float c = fmaxf((float)(e - s), 1.0f);
        v = v * Wl[f] * (1.0f / c);
#pragma unroll
        for (int off = 32; off; off >>= 1) v += __shfl_down(v, off, 64);
        if (f == 0) out[g] = 1.0f / (1.0f + expf(-(v + bl[0])));
    }
}

// ---------------- launch ----------------

extern "C" void kernel_launch(void* const* d_in, const int* in_sizes, int n_in,
                              void* d_out, int out_size, void* d_ws, size_t ws_size,
                              hipStream_t stream) {
    const float* x   = (const float*)d_in[0];
    const int* ei    = (const int*)d_in[1];
    const int* batch = (const int*)d_in[2];
    const float* W1  = (const float*)d_in[3];
    const float* b1  = (const float*)d_in[4];
    const float* W2  = (const float*)d_in[5];
    const float* b2  = (const float*)d_in[6];
    const float* Wl  = (const float*)d_in[7];
    const float* bl  = (const float*)d_in[8];
    float* out = (float*)d_out;

    const int n = in_sizes[0] / F_IN;   // 100000
    const int E = in_sizes[1] / 2;      // 1600000
    const int G = out_size;             // 512

    const int* srcp = ei;
    const int* dstp = ei + E;

    int nbuk = (n + NPB - 1) / NPB;     // 782
    int nslots = nbuk * NPB;            // 100096

    // workspace layout
    char* wsb = (char*)d_ws;
    auto alloc = [&](size_t bytes) { char* p = wsb; wsb += (bytes + 255) & ~(size_t)255; return p; };
    float* dinv       = (float*)alloc((size_t)n * 4);
    int4*  slot_hdr   = (int4*)alloc((size_t)nslots * 16);
    int*   bucket_cnt = (int*)alloc(1024 * 4);
    int*   blk_cnt    = (int*)alloc((size_t)nbuk * NB1 * 4);
    int*   pairs      = (int*)alloc((size_t)nbuk * CAP * 4);
    int*   colx       = (int*)alloc((size_t)nbuk * CAP * 4);
    unsigned short* w2t  = (unsigned short*)alloc((size_t)HDIM * HDIM * 2);
    unsigned char*  xws8 = (unsigned char*)alloc((size_t)n * HDIM);       // fp8 gather payload
    unsigned short* xh1  = (unsigned short*)alloc((size_t)n * HDIM * 2);  // layer-1 h (bf16)
    unsigned short* xh2  = (unsigned short*)alloc((size_t)n * HDIM * 2);  // layer-2 h (bf16)
    int*   gstart     = (int*)alloc(((size_t)G + 1) * 4);

    const int TB = 256;
    int gMM  = (n + 63) / 64;           // 1563
    int chunk = (E + NB1 - 1) / NB1;    // 3125
    int gG8  = (nslots * 8 + TB - 1) / TB;
    int gFront = NB1 + gMM + 16 + 3;    // hist + matmul1 + w2t + bounds

    // K1: fused front (hist ∥ matmul1-unscaled ∥ W2 transpose ∥ graph bounds)
    fused_front<<<gFront, TB, 0, stream>>>(dstp, blk_cnt, E, nbuk, chunk,
                                           x, W1, xws8, gMM, n, W2, w2t, batch, gstart, G);
    // K2-K4: CSR build
    p_scan_blocks<<<nbuk, TB, 0, stream>>>(blk_cnt, bucket_cnt);
    p1_place<<<NB1, TB, 0, stream>>>(srcp, dstp, blk_cnt, pairs, E, nbuk, chunk);
    p2_csr<<<nbuk, TB, 0, stream>>>(pairs, bucket_cnt, dinv, colx, slot_hdr, n);

    // K5: gather1 (per-edge dinv on unscaled fp8)
    csr_gather8_fp8d<<<gG8, TB, 0, stream>>>(slot_hdr, colx, dinv, (const uint2*)xws8,
                                             b1, (bf16x8*)xh1, nslots, n);
    // K6: matmul2 -> fp8 scaled
    matmul_mfma_b16<<<gMM, TB, 0, stream>>>(xh1, w2t, dinv, xws8, n);
    // K7: gather2
    csr_gather8_fp8<<<gG8, TB, 0, stream>>>(slot_hdr, colx, (const uint2*)xws8,
                                            b2, (bf16x8*)xh2, nslots, n);
    // K8: pool + head
    pool_head<<<G, TB, 0, stream>>>(xh2, gstart, Wl, bl, out, G);
}

// Round 14
// 236.433 us; speedup vs baseline: 3.4217x; 1.0425x over previous
//
#include <hip/hip_runtime.h>
#include <hip/hip_bf16.h>
#include <cmath>

#define F_IN 128
#define HDIM 64
#define NPB 128          // nodes per bucket (dst >> 7)
#define NB1 512          // partition chunks (p0 / p1_place)
#define CAP 2560         // fixed edge capacity per bucket (mean 2046, +11 sigma)

typedef __attribute__((ext_vector_type(8))) short bf16x8;
typedef __attribute__((ext_vector_type(4))) float f32x4;
typedef __attribute__((ext_vector_type(2))) float f32x2;

__device__ __forceinline__ float bf2f(unsigned short u) {
    union { unsigned int i; float f; } v; v.i = ((unsigned int)u) << 16; return v.f;
}
__device__ __forceinline__ unsigned short f2bf(float f) {
    __hip_bfloat16 h = __float2bfloat16(f);
    union { __hip_bfloat16 h; unsigned short u; } c; c.h = h; return c.u;
}
__device__ __forceinline__ unsigned char f2fp8(float f) {
    int p = __builtin_amdgcn_cvt_pk_fp8_f32(f, f, 0, false);
    return (unsigned char)(p & 0xff);
}
__device__ __forceinline__ void fp8x8_acc(uint2 v, float* a) {
    f32x2 f;
    f = __builtin_amdgcn_cvt_pk_f32_fp8(v.x, false); a[0] += f.x; a[1] += f.y;
    f = __builtin_amdgcn_cvt_pk_f32_fp8(v.x, true);  a[2] += f.x; a[3] += f.y;
    f = __builtin_amdgcn_cvt_pk_f32_fp8(v.y, false); a[4] += f.x; a[5] += f.y;
    f = __builtin_amdgcn_cvt_pk_f32_fp8(v.y, true);  a[6] += f.x; a[7] += f.y;
}

// ========== K1: per-(chunk,bucket) histogram + fused W1/W2 transpose ==========
// blocks [0,NB1): histogram; [NB1, NB1+48): w1t/w2t transposes

__launch_bounds__(256)
__global__ void p0_count(const int* __restrict__ dst, int* __restrict__ blk_cnt,
                         int E, int nbuk, int chunk,
                         const float* __restrict__ W1, const float* __restrict__ W2,
                         unsigned short* __restrict__ w1t, unsigned short* __restrict__ w2t) {
    int tid = threadIdx.x;
    if (blockIdx.x >= NB1) {
        int t = (blockIdx.x - NB1) * 256 + tid;
        if (t < F_IN * 64) {
            int c = t & 63, k = t >> 6;
            w1t[c * F_IN + k] = f2bf(W1[t]);
        } else if (t < F_IN * 64 + HDIM * 64) {
            int u = t - F_IN * 64;
            int c = u & 63, k = u >> 6;
            w2t[c * HDIM + k] = f2bf(W2[u]);
        }
        return;
    }
    __shared__ int hist[1024];
    for (int i = tid; i < nbuk; i += 256) hist[i] = 0;
    __syncthreads();
    int lo = blockIdx.x * chunk, hi = min(E, lo + chunk);
    for (int e = lo + tid; e < hi; e += 256)
        atomicAdd(&hist[dst[e] >> 7], 1);
    __syncthreads();
    for (int i = tid; i < nbuk; i += 256)
        blk_cnt[(size_t)i * NB1 + blockIdx.x] = hist[i];
}

// ========== K2: per-bucket scan over chunks + fused graph bounds ==========

__launch_bounds__(256)
__global__ void p_scan_blocks(int* __restrict__ blk_cnt, int* __restrict__ bucket_cnt,
                              int nbuk, const int* __restrict__ batch,
                              int* __restrict__ gstart, int n, int G) {
    int tid = threadIdx.x;
    if (blockIdx.x >= nbuk) {
        int g = (blockIdx.x - nbuk) * 256 + tid;
        if (g > G) return;
        int lo = 0, hi = n;
        while (lo < hi) {
            int mid = (lo + hi) >> 1;
            if (batch[mid] < g) lo = mid + 1; else hi = mid;
        }
        gstart[g] = lo;
        return;
    }
    __shared__ int sd[256];
    int b = blockIdx.x;
    int2* row = (int2*)(blk_cnt + (size_t)b * NB1);
    int2 v = row[tid];
    int s0 = v.x, s1 = s0 + v.y;
    sd[tid] = s1;
    __syncthreads();
    for (int off = 1; off < 256; off <<= 1) {
        int a = (tid >= off) ? sd[tid - off] : 0;
        __syncthreads();
        sd[tid] += a;
        __syncthreads();
    }
    int base = sd[tid] - s1;
    row[tid] = make_int2(base, base + s0);
    if (tid == 255) bucket_cnt[b] = sd[255];
}

// ========== K3: place edges (fixed bucket base, LDS-only atomics) ==========

__launch_bounds__(256)
__global__ void p1_place(const int* __restrict__ src, const int* __restrict__ dst,
                         const int* __restrict__ blk_cnt, int* __restrict__ pairs,
                         int E, int nbuk, int chunk) {
    __shared__ int cur[1024];
    int tid = threadIdx.x;
    for (int i = tid; i < nbuk; i += 256)
        cur[i] = i * CAP + blk_cnt[(size_t)i * NB1 + blockIdx.x];
    __syncthreads();
    int lo = blockIdx.x * chunk, hi = min(E, lo + chunk);
    for (int e = lo + tid; e < hi; e += 256) {
        int d = dst[e];
        int pos = atomicAdd(&cur[d >> 7], 1);
        pairs[pos] = (src[e] << 7) | (d & 127);
    }
}

// ========== K4: per-bucket local CSR + degree-sorted slot headers ==========

__launch_bounds__(256)
__global__ void p2_csr(const int* __restrict__ pairs, const int* __restrict__ bucket_cnt,
                       float* __restrict__ dinv, int* __restrict__ col,
                       int4* __restrict__ slot_hdr, int n) {
    __shared__ int dl[128];
    __shared__ int sc[128];
    __shared__ int cur[128];
    __shared__ int h64[64];
    __shared__ int s64[64];
    int b = blockIdx.x, tid = threadIdx.x;
    int nlo = b << 7;
    int eb = b * CAP;
    int ee = eb + bucket_cnt[b];
    if (tid < 128) dl[tid] = 0;
    if (tid < 64) h64[tid] = 0;
    __syncthreads();
    for (int e = eb + tid; e < ee; e += 256)
        atomicAdd(&dl[pairs[e] & 127], 1);
    __syncthreads();
    int d0 = 0, excl = 0;
    if (tid < 128) { d0 = dl[tid]; sc[tid] = d0; }
    __syncthreads();
    for (int off = 1; off < 128; off <<= 1) {
        int a = (tid >= off && tid < 128) ? sc[tid - off] : 0;
        __syncthreads();
        if (tid < 128) sc[tid] += a;
        __syncthreads();
    }
    if (tid < 128) {
        excl = sc[tid] - d0;
        int node = nlo + tid;
        float dv = rsqrtf((float)(d0 + 1));
        if (node < n) dinv[node] = dv;
        cur[tid] = eb + excl;
        atomicAdd(&h64[min(d0, 63)], 1);
    }
    __syncthreads();
    if (tid == 0) { int run = 0; for (int i = 0; i < 64; ++i) { s64[i] = run; run += h64[i]; } }
    __syncthreads();
    if (tid < 64) h64[tid] = 0;
    __syncthreads();
    if (tid < 128) {
        int node = nlo + tid;
        int bin = min(d0, 63);
        int pos = s64[bin] + atomicAdd(&h64[bin], 1);
        int4 hdr;
        hdr.x = (node < n) ? node : 0x7fffffff;
        hdr.y = eb + excl;
        hdr.z = d0;
        hdr.w = __float_as_int(rsqrtf((float)(d0 + 1)));
        slot_hdr[nlo + pos] = hdr;
    }
    __syncthreads();
    for (int e = eb + tid; e < ee; e += 256) {
        unsigned int v = (unsigned int)pairs[e];
        int pos = atomicAdd(&cur[v & 127], 1);
        col[pos] = (int)(v >> 7);
    }
}

// ========== K5: matmul1 (f32 X, K=128) -> fp8(xw * dinv) ==========

template <int K>
__launch_bounds__(256)
__global__ void matmul_mfma(const float* __restrict__ X, const unsigned short* __restrict__ Wt,
                            const float* __restrict__ dinv, unsigned char* __restrict__ out,
                            int n) {
    constexpr int KS  = K / 32;
    constexpr int LDX = K + 8;
    __shared__ unsigned short Xs[64 * LDX];
    __shared__ unsigned short Ws[64 * LDX];
    int tid = threadIdx.x;
    int rowbase = blockIdx.x * 64;
    for (int i = tid; i < 64 * (K / 8); i += 256) {
        int r = i / (K / 8), ch = i % (K / 8);
        *(bf16x8*)(Ws + r * LDX + ch * 8) = ((const bf16x8*)Wt)[i];
    }
    {
        const float4* X4 = (const float4*)X;
        for (int i = tid; i < 64 * (K / 4); i += 256) {
            int r = i / (K / 4), k4 = i % (K / 4);
            ushort4 u = { 0, 0, 0, 0 };
            int gr = rowbase + r;
            if (gr < n) {
                float4 v = X4[(size_t)gr * (K / 4) + k4];
                u.x = f2bf(v.x); u.y = f2bf(v.y); u.z = f2bf(v.z); u.w = f2bf(v.w);
            }
            *(ushort4*)(Xs + r * LDX + k4 * 4) = u;
        }
    }
    __syncthreads();
    int wave = tid >> 6, lane = tid & 63;
    int q = lane >> 4, nn = lane & 15;
    f32x4 acc[4] = {{0,0,0,0},{0,0,0,0},{0,0,0,0},{0,0,0,0}};
    int mrow = wave * 16 + nn;
#pragma unroll
    for (int s = 0; s < KS; ++s) {
        bf16x8 af = *(const bf16x8*)(Xs + mrow * LDX + s * 32 + q * 8);
#pragma unroll
        for (int c = 0; c < 4; ++c) {
            bf16x8 bf = *(const bf16x8*)(Ws + (c * 16 + nn) * LDX + s * 32 + q * 8);
            acc[c] = __builtin_amdgcn_mfma_f32_16x16x32_bf16(af, bf, acc[c], 0, 0, 0);
        }
    }
#pragma unroll
    for (int r = 0; r < 4; ++r) {
        int row = rowbase + wave * 16 + q * 4 + r;
        if (row >= n) continue;
        float dv = dinv[row];
#pragma unroll
        for (int c = 0; c < 4; ++c)
            out[(size_t)row * HDIM + c * 16 + nn] = f2fp8(acc[c][r] * dv);
    }
}

// ========== K6: gather1 + fused matmul2 ==========
// Block = 32 slots x 8 lanes. Gather h1 rows (fp8 payload, relu+bias), stash h1 (bf16)
// in LDS, then 4 waves MFMA the 32x64 tile against W2 and emit fp8(h2w * dinv) directly.

__launch_bounds__(256)
__global__ void gather1_mm2(const int4* __restrict__ slot_hdr, const int* __restrict__ col,
                            const uint2* __restrict__ xws, const float* __restrict__ bias,
                            const unsigned short* __restrict__ w2t,
                            unsigned char* __restrict__ out8, int nslots, int n) {
    __shared__ unsigned short Hs[32 * 72];   // h1 tile, bf16, row stride 72
    __shared__ unsigned short Ws[64 * 72];   // W2^T rows: Ws[c][k]
    __shared__ int   snode[32];
    __shared__ float sdinv[32];

    int tid = threadIdx.x;
    int ls = tid >> 3;          // local slot 0..31
    int L  = tid & 7;           // feature-octet lane
    int slot = blockIdx.x * 32 + ls;

    // stage W2t (bf16x8 chunks: 64 rows x 8 chunks)
    for (int i = tid; i < 64 * 8; i += 256) {
        int r = i >> 3, ch = i & 7;
        *(bf16x8*)(Ws + r * 72 + ch * 8) = ((const bf16x8*)w2t)[i];
    }

    // ---- gather phase ----
    int node = 0x7fffffff;
    float dv = 0.0f;
    float a[8] = {0, 0, 0, 0, 0, 0, 0, 0};
    if (slot < nslots) {
        int4 hdr = slot_hdr[slot];
        node = hdr.x;
        if (node < n) {
            int s = hdr.y, end = s + hdr.z;
            dv = __int_as_float(hdr.w);
            fp8x8_acc(xws[(size_t)node * 8 + L], a);   // self-loop term
            int e = s;
            for (; e + 8 <= end; e += 8) {
                uint2 v0 = xws[(size_t)col[e + 0] * 8 + L];
                uint2 v1 = xws[(size_t)col[e + 1] * 8 + L];
                uint2 v2 = xws[(size_t)col[e + 2] * 8 + L];
                uint2 v3 = xws[(size_t)col[e + 3] * 8 + L];
                uint2 v4 = xws[(size_t)col[e + 4] * 8 + L];
                uint2 v5 = xws[(size_t)col[e + 5] * 8 + L];
                uint2 v6 = xws[(size_t)col[e + 6] * 8 + L];
                uint2 v7 = xws[(size_t)col[e + 7] * 8 + L];
                fp8x8_acc(v0, a); fp8x8_acc(v1, a); fp8x8_acc(v2, a); fp8x8_acc(v3, a);
                fp8x8_acc(v4, a); fp8x8_acc(v5, a); fp8x8_acc(v6, a); fp8x8_acc(v7, a);
            }
            for (; e < end; ++e)
                fp8x8_acc(xws[(size_t)col[e] * 8 + L], a);
        }
    }
    if (L == 0) { snode[ls] = node; sdinv[ls] = dv; }
    // h1 row (bf16) -> LDS (zeros for invalid slots)
    {
        int f0 = L * 8;
        bf16x8 o;
        if (node < n) {
#pragma unroll
            for (int j = 0; j < 8; ++j)
                o[j] = (short)f2bf(fmaxf(fmaf(a[j], dv, bias[f0 + j]), 0.0f));
        } else {
            short z[8] = {0,0,0,0,0,0,0,0};
            o = *(bf16x8*)z;
        }
        *(bf16x8*)(Hs + ls * 72 + L * 8) = o;
    }
    __syncthreads();

    // ---- matmul2 phase: D[32x64] = Hs @ W2, scaled by sdinv, emit fp8 ----
    int wave = tid >> 6, lane = tid & 63;
    int q = lane >> 4, nn = lane & 15;
    int mt  = wave & 1;          // M-tile (rows 0-15 / 16-31)
    int nt0 = (wave >> 1) * 2;   // N-tiles {nt0, nt0+1}
    f32x4 acc[2] = {{0,0,0,0},{0,0,0,0}};
#pragma unroll
    for (int s = 0; s < 2; ++s) {
        bf16x8 af = *(const bf16x8*)(Hs + (mt * 16 + nn) * 72 + s * 32 + q * 8);
#pragma unroll
        for (int t = 0; t < 2; ++t) {
            bf16x8 bf = *(const bf16x8*)(Ws + ((nt0 + t) * 16 + nn) * 72 + s * 32 + q * 8);
            acc[t] = __builtin_amdgcn_mfma_f32_16x16x32_bf16(af, bf, acc[t], 0, 0, 0);
        }
    }
#pragma unroll
    for (int r = 0; r < 4; ++r) {
        int lslot = mt * 16 + q * 4 + r;
        int nd = snode[lslot];
        if (nd >= n) continue;
        float dvr = sdinv[lslot];
#pragma unroll
        for (int t = 0; t < 2; ++t)
            out8[(size_t)nd * HDIM + (nt0 + t) * 16 + nn] = f2fp8(acc[t][r] * dvr);
    }
}

// ========== K7: gather2 (fp8 pre-scaled rows) -> bf16 h2 ==========

__launch_bounds__(256)
__global__ void csr_gather8_fp8(const int4* __restrict__ slot_hdr, const int* __restrict__ col,
                                const uint2* __restrict__ xws, const float* __restrict__ bias,
                                bf16x8* __restrict__ outb, int nslots, int n) {
    int t = blockIdx.x * 256 + threadIdx.x;
    int slot = t >> 3;
    if (slot >= nslots) return;
    int L = t & 7;
    int4 hdr = slot_hdr[slot];
    int node = hdr.x;
    if (node >= n) return;
    int s = hdr.y, end = s + hdr.z;
    float dv = __int_as_float(hdr.w);

    float a[8] = {0, 0, 0, 0, 0, 0, 0, 0};
    fp8x8_acc(xws[(size_t)node * 8 + L], a);
    int e = s;
    for (; e + 8 <= end; e += 8) {
        uint2 v0 = xws[(size_t)col[e + 0] * 8 + L];
        uint2 v1 = xws[(size_t)col[e + 1] * 8 + L];
        uint2 v2 = xws[(size_t)col[e + 2] * 8 + L];
        uint2 v3 = xws[(size_t)col[e + 3] * 8 + L];
        uint2 v4 = xws[(size_t)col[e + 4] * 8 + L];
        uint2 v5 = xws[(size_t)col[e + 5] * 8 + L];
        uint2 v6 = xws[(size_t)col[e + 6] * 8 + L];
        uint2 v7 = xws[(size_t)col[e + 7] * 8 + L];
        fp8x8_acc(v0, a); fp8x8_acc(v1, a); fp8x8_acc(v2, a); fp8x8_acc(v3, a);
        fp8x8_acc(v4, a); fp8x8_acc(v5, a); fp8x8_acc(v6, a); fp8x8_acc(v7, a);
    }
    for (; e < end; ++e)
        fp8x8_acc(xws[(size_t)col[e] * 8 + L], a);

    int f0 = L * 8;
    bf16x8 o;
#pragma unroll
    for (int j = 0; j < 8; ++j)
        o[j] = (short)f2bf(fmaxf(fmaf(a[j], dv, bias[f0 + j]), 0.0f));
    outb[(size_t)node * 8 + L] = o;
}

// ========== K8: mean-pool (bf16 rows) + head + sigmoid ==========

__launch_bounds__(256)
__global__ void pool_head(const unsigned short* __restrict__ h, const int* __restrict__ gstart,
                          const float* __restrict__ Wl, const float* __restrict__ bl,
                          float* __restrict__ out, int G) {
    int g = blockIdx.x;
    int s = gstart[g], e = gstart[g + 1];
    int f  = threadIdx.x & 63;
    int rg = threadIdx.x >> 6;
    float acc = 0.0f;
    for (int i = s + rg; i < e; i += 4)
        acc += bf2f(h[(size_t)i * HDIM + f]);
    __shared__ float red[4][HDIM];
    red[rg][f] = acc;
    __syncthreads();
    if (rg == 0) {
        float v = (red[0][f] + red[1][f]) + (red[2][f] + red[3][f]);
        float c = fmaxf((float)(e - s), 1.0f);
        v = v * Wl[f] * (1.0f / c);
#pragma unroll
        for (int off = 32; off; off >>= 1) v += __shfl_down(v, off, 64);
        if (f == 0) out[g] = 1.0f / (1.0f + expf(-(v + bl[0])));
    }
}

// ---------------- launch ----------------

extern "C" void kernel_launch(void* const* d_in, const int* in_sizes, int n_in,
                              void* d_out, int out_size, void* d_ws, size_t ws_size,
                              hipStream_t stream) {
    const float* x   = (const float*)d_in[0];
    const int* ei    = (const int*)d_in[1];
    const int* batch = (const int*)d_in[2];
    const float* W1  = (const float*)d_in[3];
    const float* b1  = (const float*)d_in[4];
    const float* W2  = (const float*)d_in[5];
    const float* b2  = (const float*)d_in[6];
    const float* Wl  = (const float*)d_in[7];
    const float* bl  = (const float*)d_in[8];
    float* out = (float*)d_out;

    const int n = in_sizes[0] / F_IN;   // 100000
    const int E = in_sizes[1] / 2;      // 1600000
    const int G = out_size;             // 512

    const int* srcp = ei;
    const int* dstp = ei + E;

    int nbuk = (n + NPB - 1) / NPB;     // 782
    int nslots = nbuk * NPB;            // 100096

    // workspace layout
    char* wsb = (char*)d_ws;
    auto alloc = [&](size_t bytes) { char* p = wsb; wsb += (bytes + 255) & ~(size_t)255; return p; };
    float* dinv       = (float*)alloc((size_t)n * 4);
    int4*  slot_hdr   = (int4*)alloc((size_t)nslots * 16);
    int*   bucket_cnt = (int*)alloc(1024 * 4);
    int*   blk_cnt    = (int*)alloc((size_t)nbuk * NB1 * 4);
    int*   pairs      = (int*)alloc((size_t)nbuk * CAP * 4);
    int*   colx       = (int*)alloc((size_t)nbuk * CAP * 4);
    unsigned short* w1t  = (unsigned short*)alloc((size_t)F_IN * HDIM * 2);
    unsigned short* w2t  = (unsigned short*)alloc((size_t)HDIM * HDIM * 2);
    unsigned char*  xws8 = (unsigned char*)alloc((size_t)n * HDIM);       // fp8 payload L1
    unsigned char*  xws8b= (unsigned char*)alloc((size_t)n * HDIM);       // fp8 payload L2
    unsigned short* xh2  = (unsigned short*)alloc((size_t)n * HDIM * 2);  // layer-2 h (bf16)
    int*   gstart     = (int*)alloc(((size_t)G + 1) * 4);

    const int TB = 256;
    int gMM  = (n + 63) / 64;           // 1563
    int chunk = (E + NB1 - 1) / NB1;    // 3125
    int gG8  = (nslots * 8 + TB - 1) / TB;   // 3128
    int gS   = (nslots + 31) / 32;           // 3128

    // CSR build (+ fused transposes / bounds)
    p0_count<<<NB1 + 48, TB, 0, stream>>>(dstp, blk_cnt, E, nbuk, chunk, W1, W2, w1t, w2t);
    p_scan_blocks<<<nbuk + 3, TB, 0, stream>>>(blk_cnt, bucket_cnt, nbuk, batch, gstart, n, G);
    p1_place<<<NB1, TB, 0, stream>>>(srcp, dstp, blk_cnt, pairs, E, nbuk, chunk);
    p2_csr<<<nbuk, TB, 0, stream>>>(pairs, bucket_cnt, dinv, colx, slot_hdr, n);

    // layer 1 matmul -> fp8 scaled payload
    matmul_mfma<F_IN><<<gMM, TB, 0, stream>>>(x, w1t, dinv, xws8, n);
    // gather1 + fused matmul2 -> fp8 scaled layer-2 payload
    gather1_mm2<<<gS, TB, 0, stream>>>(slot_hdr, colx, (const uint2*)xws8,
                                       b1, w2t, xws8b, nslots, n);
    // gather2 -> bf16 h2
    csr_gather8_fp8<<<gG8, TB, 0, stream>>>(slot_hdr, colx, (const uint2*)xws8b,
                                            b2, (bf16x8*)xh2, nslots, n);
    // pool + head
    pool_head<<<G, TB, 0, stream>>>(xh2, gstart, Wl, bl, out, G);
}